// Round 2
// baseline (847.364 us; speedup 1.0000x reference)
//
#include <hip/hip_runtime.h>

#define N_NODES 4096
#define C_CH    128
#define E_ELEM  10
#define NP      4736          // padded sorted-node space (64-aligned per element)
#define TT      219           // 9 deg1 + 45 deg2 + 165 deg3 monomials
#define PSTRIDE (TT * 4)      // 876 floats per (e,c): [t][m], m0=L0, m1..3=L1
#define MAXCHUNK 64

// ws layout (bytes):
//   0       hist[10]
//   64      pstart[11]      (64-aligned padded starts)
//   128     pcursor[10]
//   256     chunk_e[64]
//   512     chunk_j0[64]
//   768     chunk_n2[64]
//   1024    jlist_p[4736]   (-1 = pad slot)
//   20480   elem[4096]
//   36864   S31[3465]   symmetrized U3_1  [m][t3][7]
//   50752   S30[825]    symmetrized U3_0  [t3][5]
//   54080   S21[405]    symmetrized U2_1  [m][t2][3]
//   55712   S20[90]     symmetrized U2_0  [t2][2]
//   57344   P[1280*876] per-(e,c) poly coeffs [ec][t][4]
//   4542464 bout[512*4736]  [c*4+slot][j]
#define WS_HIST    0
#define WS_PSTART  64
#define WS_PCUR    128
#define WS_CHE     256
#define WS_CHJ     512
#define WS_CHN     768
#define WS_JLIST   1024
#define WS_ELEM    20480
#define WS_S31     36864
#define WS_S30     50752
#define WS_S21     54080
#define WS_S20     55712
#define WS_P       57344
#define WS_BOUT    4542464

__global__ void k_elem_hist(const float* __restrict__ attrs, int* __restrict__ elem,
                            int* __restrict__ hist, int* __restrict__ jlist) {
    int n = blockIdx.x * blockDim.x + threadIdx.x;
    if (n < NP) jlist[n] = -1;            // pad fill (runs before k_scatter)
    if (n >= N_NODES) return;
    const float* a = attrs + n * E_ELEM;
    float best = a[0];
    int e = 0;
#pragma unroll
    for (int k = 1; k < E_ELEM; ++k) {
        float v = a[k];
        if (v > best) { best = v; e = k; }
    }
    elem[n] = e;
    atomicAdd(&hist[e], 1);
}

__global__ void k_prefix(const int* __restrict__ hist, int* __restrict__ pstart,
                         int* __restrict__ pcursor, int* __restrict__ chE,
                         int* __restrict__ chJ, int* __restrict__ chN) {
    if (threadIdx.x != 0) return;
    int s = 0;
    for (int e = 0; e < E_ELEM; ++e) {
        pstart[e] = s;
        pcursor[e] = s;
        int plen = ((hist[e] + 63) >> 6) << 6;   // 64-align each element range
        s += plen;
    }
    pstart[E_ELEM] = s;
    int ci = 0;
    for (int e = 0; e < E_ELEM; ++e) {
        int base = pstart[e];
        int plen = pstart[e + 1] - base;
        for (int ofs = 0; ofs < plen; ofs += 128) {
            chE[ci] = e;
            chJ[ci] = base + ofs;
            chN[ci] = (plen - ofs) > 64 ? 2 : 1;
            ++ci;
        }
    }
    for (; ci < MAXCHUNK; ++ci) chE[ci] = -1;
}

__global__ void k_scatter(const int* __restrict__ elem, int* __restrict__ pcursor,
                          int* __restrict__ jlist) {
    int n = blockIdx.x * blockDim.x + threadIdx.x;
    if (n >= N_NODES) return;
    int e = elem[n];
    int pos = atomicAdd(&pcursor[e], 1);
    jlist[pos] = n;
}

// Symmetrize U tensors over monomial multisets (lex order a<=b<=i, a-major).
__global__ void k_sym(const float* __restrict__ U3_1, const float* __restrict__ U3_0,
                      const float* __restrict__ U2_1, const float* __restrict__ U2_0,
                      float* __restrict__ S31, float* __restrict__ S30,
                      float* __restrict__ S21, float* __restrict__ S20) {
    __shared__ int t3tab[165];
    __shared__ int t2tab[45];
    int tid = threadIdx.x;
    if (tid < 165) {
        int cnt = 0;
        for (int a = 0; a < 9; ++a)
            for (int b = a; b < 9; ++b)
                for (int i = b; i < 9; ++i) {
                    if (cnt == tid) t3tab[tid] = a | (b << 4) | (i << 8);
                    ++cnt;
                }
    }
    if (tid < 45) {
        int cnt = 0;
        for (int a = 0; a < 9; ++a)
            for (int b = a; b < 9; ++b) {
                if (cnt == tid) t2tab[tid] = a | (b << 4);
                ++cnt;
            }
    }
    __syncthreads();
    for (int q = tid; q < 3465; q += 256) {        // S31 [m][t][p], p=7
        int m = q / 1155, r = q % 1155, t = r / 7, p = r % 7;
        int tr = t3tab[t];
        int a = tr & 15, b = (tr >> 4) & 15, i = (tr >> 8) & 15;
#define U31(X, Y, Z) U3_1[((((m * 9 + (X)) * 9 + (Y)) * 9 + (Z)) * 7) + p]
        float s = U31(a, b, i);
        if (a == b && b == i) {}
        else if (a == b) s += U31(a, i, a) + U31(i, a, a);
        else if (b == i) s += U31(b, a, b) + U31(b, b, a);
        else s += U31(a, i, b) + U31(b, a, i) + U31(b, i, a) + U31(i, a, b) + U31(i, b, a);
#undef U31
        S31[q] = s;
    }
    for (int q = tid; q < 825; q += 256) {         // S30 [t][p], p=5
        int t = q / 5, p = q % 5;
        int tr = t3tab[t];
        int a = tr & 15, b = (tr >> 4) & 15, i = (tr >> 8) & 15;
#define U30(X, Y, Z) U3_0[((((X) * 9 + (Y)) * 9 + (Z)) * 5) + p]
        float s = U30(a, b, i);
        if (a == b && b == i) {}
        else if (a == b) s += U30(a, i, a) + U30(i, a, a);
        else if (b == i) s += U30(b, a, b) + U30(b, b, a);
        else s += U30(a, i, b) + U30(b, a, i) + U30(b, i, a) + U30(i, a, b) + U30(i, b, a);
#undef U30
        S30[q] = s;
    }
    for (int q = tid; q < 405; q += 256) {         // S21 [m][t][p], p=3
        int m = q / 135, r = q % 135, t = r / 3, p = r % 3;
        int tr = t2tab[t];
        int a = tr & 15, b = (tr >> 4) & 15;
        float s = U2_1[(((m * 9 + a) * 9 + b) * 3) + p];
        if (a != b) s += U2_1[(((m * 9 + b) * 9 + a) * 3) + p];
        S21[q] = s;
    }
    for (int q = tid; q < 90; q += 256) {          // S20 [t][p], p=2
        int t = q / 2, p = q % 2;
        int tr = t2tab[t];
        int a = tr & 15, b = (tr >> 4) & 15;
        float s = U2_0[((a * 9 + b) * 2) + p];
        if (a != b) s += U2_0[((b * 9 + a) * 2) + p];
        S20[q] = s;
    }
}

// Fold element weights into symmetrized basis: P[e*128+c][t][m]
__global__ __launch_bounds__(128) void k_fold(
    const float* __restrict__ S31, const float* __restrict__ S30,
    const float* __restrict__ S21, const float* __restrict__ S20,
    const float* __restrict__ U1_1, const float* __restrict__ U1_0,
    const float* __restrict__ W3_1, const float* __restrict__ W3_0,
    const float* __restrict__ W2_1, const float* __restrict__ W2_0,
    const float* __restrict__ W1_1, const float* __restrict__ W1_0,
    float* __restrict__ P) {
    int e = blockIdx.x >> 7;
    int c = blockIdx.x & 127;
    float* Pout = P + (size_t)blockIdx.x * PSTRIDE;
    for (int q = threadIdx.x; q < PSTRIDE; q += 128) {
        int t = q >> 2, m = q & 3;
        float v;
        if (t < 9) {
            int a = t;
            v = (m == 0) ? U1_0[a] * W1_0[e * C_CH + c]
                         : U1_1[(m - 1) * 9 + a] * W1_1[e * C_CH + c];
        } else if (t < 54) {
            int t2 = t - 9;
            float s = 0.f;
            if (m == 0) {
#pragma unroll
                for (int p = 0; p < 2; ++p)
                    s = fmaf(S20[t2 * 2 + p], W2_0[(e * 2 + p) * C_CH + c], s);
            } else {
#pragma unroll
                for (int p = 0; p < 3; ++p)
                    s = fmaf(S21[((m - 1) * 45 + t2) * 3 + p], W2_1[(e * 3 + p) * C_CH + c], s);
            }
            v = s;
        } else {
            int t3 = t - 54;
            float s = 0.f;
            if (m == 0) {
#pragma unroll
                for (int p = 0; p < 5; ++p)
                    s = fmaf(S30[t3 * 5 + p], W3_0[(e * 5 + p) * C_CH + c], s);
            } else {
#pragma unroll
                for (int p = 0; p < 7; ++p)
                    s = fmaf(S31[((m - 1) * 165 + t3) * 7 + p], W3_1[(e * 7 + p) * C_CH + c], s);
            }
            v = s;
        }
        Pout[q] = v;
    }
}

template <int NN>
__device__ __forceinline__ void poly_eval(const float* __restrict__ sP,
                                          const float (&xv)[NN][9], float (&acc)[NN][4]) {
    const float* p1 = sP;
    const float* p2 = sP + 9 * 4;
    const float* p3 = sP + 54 * 4;
    int i2 = 0, i3 = 0;
#pragma unroll
    for (int a = 0; a < 9; ++a) {
        float4 q1 = *(const float4*)(p1 + a * 4);
#pragma unroll
        for (int u = 0; u < NN; ++u) {
            float xa = xv[u][a];
            acc[u][0] = fmaf(q1.x, xa, acc[u][0]);
            acc[u][1] = fmaf(q1.y, xa, acc[u][1]);
            acc[u][2] = fmaf(q1.z, xa, acc[u][2]);
            acc[u][3] = fmaf(q1.w, xa, acc[u][3]);
        }
#pragma unroll
        for (int b = a; b < 9; ++b) {
            float m2[NN];
            float4 q2 = *(const float4*)(p2 + i2 * 4);
            ++i2;
#pragma unroll
            for (int u = 0; u < NN; ++u) {
                m2[u] = xv[u][a] * xv[u][b];
                acc[u][0] = fmaf(q2.x, m2[u], acc[u][0]);
                acc[u][1] = fmaf(q2.y, m2[u], acc[u][1]);
                acc[u][2] = fmaf(q2.z, m2[u], acc[u][2]);
                acc[u][3] = fmaf(q2.w, m2[u], acc[u][3]);
            }
#pragma unroll
            for (int i = b; i < 9; ++i) {
                float4 q3 = *(const float4*)(p3 + i3 * 4);
                ++i3;
#pragma unroll
                for (int u = 0; u < NN; ++u) {
                    float m3 = m2[u] * xv[u][i];
                    acc[u][0] = fmaf(q3.x, m3, acc[u][0]);
                    acc[u][1] = fmaf(q3.y, m3, acc[u][1]);
                    acc[u][2] = fmaf(q3.z, m3, acc[u][2]);
                    acc[u][3] = fmaf(q3.w, m3, acc[u][3]);
                }
            }
        }
    }
}

__global__ __launch_bounds__(64) void k_poly(
    const float* __restrict__ x, const int* __restrict__ jlist,
    const int* __restrict__ chE, const int* __restrict__ chJ,
    const int* __restrict__ chN, const float* __restrict__ P,
    float* __restrict__ bout) {
    int ci = blockIdx.y;
    int e = chE[ci];
    if (e < 0) return;
    int c = blockIdx.x;
    __shared__ __align__(16) float sP[PSTRIDE];
    const float* Pg = P + (size_t)(e * C_CH + c) * PSTRIDE;
    for (int t = threadIdx.x; t < PSTRIDE; t += 64) sP[t] = Pg[t];
    __syncthreads();
    int j0 = chJ[ci] + threadIdx.x;
    if (chN[ci] == 2) {
        int jA = j0, jB = j0 + 64;
        int nA = jlist[jA], nB = jlist[jB];
        bool vA = nA >= 0, vB = nB >= 0;
        nA = vA ? nA : 0;
        nB = vB ? nB : 0;
        const float* pA = x + (size_t)(nA * C_CH + c) * 9;
        const float* pB = x + (size_t)(nB * C_CH + c) * 9;
        float xv[2][9];
        float acc[2][4] = {};
#pragma unroll
        for (int i = 0; i < 9; ++i) { xv[0][i] = pA[i]; xv[1][i] = pB[i]; }
        poly_eval<2>(sP, xv, acc);
        if (vA) {
#pragma unroll
            for (int m = 0; m < 4; ++m) bout[(size_t)(c * 4 + m) * NP + jA] = acc[0][m];
        }
        if (vB) {
#pragma unroll
            for (int m = 0; m < 4; ++m) bout[(size_t)(c * 4 + m) * NP + jB] = acc[1][m];
        }
    } else {
        int jA = j0;
        int nA = jlist[jA];
        bool vA = nA >= 0;
        nA = vA ? nA : 0;
        const float* pA = x + (size_t)(nA * C_CH + c) * 9;
        float xv[1][9];
        float acc[1][4] = {};
#pragma unroll
        for (int i = 0; i < 9; ++i) xv[0][i] = pA[i];
        poly_eval<1>(sP, xv, acc);
        if (vA) {
#pragma unroll
            for (int m = 0; m < 4; ++m) bout[(size_t)(c * 4 + m) * NP + jA] = acc[0][m];
        }
    }
}

__global__ __launch_bounds__(512) void k_linear(
    const float* __restrict__ bout, const int* __restrict__ jlist,
    const float* __restrict__ Wl0, const float* __restrict__ Wl1,
    const float* __restrict__ sc, float* __restrict__ out) {
    const int col = threadIdx.x;
    const int jbase = blockIdx.x * 16;
    int d, slot;
    const float* Wl;
    if (col < 128) { d = col; slot = 0; Wl = Wl0; }
    else {
        int q = col - 128;
        d = q / 3;
        slot = 1 + q % 3;
        Wl = Wl1;
    }
    float acc[16];
#pragma unroll
    for (int q = 0; q < 16; ++q) acc[q] = 0.f;

    for (int cc = 0; cc < C_CH; ++cc) {
        float w = Wl[cc * C_CH + d];
        const float4* bp =
            reinterpret_cast<const float4*>(bout + (size_t)(cc * 4 + slot) * NP + jbase);
#pragma unroll
        for (int q = 0; q < 4; ++q) {
            float4 v = bp[q];
            acc[q * 4 + 0] = fmaf(w, v.x, acc[q * 4 + 0]);
            acc[q * 4 + 1] = fmaf(w, v.y, acc[q * 4 + 1]);
            acc[q * 4 + 2] = fmaf(w, v.z, acc[q * 4 + 2]);
            acc[q * 4 + 3] = fmaf(w, v.w, acc[q * 4 + 3]);
        }
    }

    const float inv = 0.08838834764831845f;  // 1/sqrt(128)
#pragma unroll
    for (int jj = 0; jj < 16; ++jj) {
        int n = jlist[jbase + jj];
        if (n >= 0) out[n * 512 + col] = fmaf(acc[jj], inv, sc[n * 512 + col]);
    }
}

extern "C" void kernel_launch(void* const* d_in, const int* in_sizes, int n_in,
                              void* d_out, int out_size, void* d_ws, size_t ws_size,
                              hipStream_t stream) {
    const float* x     = (const float*)d_in[0];
    const float* sc    = (const float*)d_in[1];
    const float* attrs = (const float*)d_in[2];
    const float* U3_0 = (const float*)d_in[3];
    const float* U2_0 = (const float*)d_in[4];
    const float* U1_0 = (const float*)d_in[5];
    const float* W3_0 = (const float*)d_in[6];
    const float* W2_0 = (const float*)d_in[7];
    const float* W1_0 = (const float*)d_in[8];
    const float* Wl0  = (const float*)d_in[9];
    const float* U3_1 = (const float*)d_in[10];
    const float* U2_1 = (const float*)d_in[11];
    const float* U1_1 = (const float*)d_in[12];
    const float* W3_1 = (const float*)d_in[13];
    const float* W2_1 = (const float*)d_in[14];
    const float* W1_1 = (const float*)d_in[15];
    const float* Wl1  = (const float*)d_in[16];

    char* ws = (char*)d_ws;
    int* hist    = (int*)(ws + WS_HIST);
    int* pstart  = (int*)(ws + WS_PSTART);
    int* pcursor = (int*)(ws + WS_PCUR);
    int* chE     = (int*)(ws + WS_CHE);
    int* chJ     = (int*)(ws + WS_CHJ);
    int* chN     = (int*)(ws + WS_CHN);
    int* jlist   = (int*)(ws + WS_JLIST);
    int* elem    = (int*)(ws + WS_ELEM);
    float* S31   = (float*)(ws + WS_S31);
    float* S30   = (float*)(ws + WS_S30);
    float* S21   = (float*)(ws + WS_S21);
    float* S20   = (float*)(ws + WS_S20);
    float* P     = (float*)(ws + WS_P);
    float* bout  = (float*)(ws + WS_BOUT);

    hipMemsetAsync(hist, 0, E_ELEM * sizeof(int), stream);
    k_elem_hist<<<(NP + 255) / 256, 256, 0, stream>>>(attrs, elem, hist, jlist);
    k_prefix<<<1, 64, 0, stream>>>(hist, pstart, pcursor, chE, chJ, chN);
    k_scatter<<<16, 256, 0, stream>>>(elem, pcursor, jlist);
    k_sym<<<1, 256, 0, stream>>>(U3_1, U3_0, U2_1, U2_0, S31, S30, S21, S20);
    k_fold<<<1280, 128, 0, stream>>>(S31, S30, S21, S20, U1_1, U1_0,
                                     W3_1, W3_0, W2_1, W2_0, W1_1, W1_0, P);
    k_poly<<<dim3(128, MAXCHUNK), 64, 0, stream>>>(x, jlist, chE, chJ, chN, P, bout);
    k_linear<<<(NP / 16), 512, 0, stream>>>(bout, jlist, Wl0, Wl1, sc, (float*)d_out);
}